// Round 5
// baseline (179.758 us; speedup 1.0000x reference)
//
#include <hip/hip_runtime.h>

#define N_HID 128
#define CAP   32          // bucket slots per node = exactly one 64B line (ushort)
#define OVF_CAP 8192
#define NSLICE 8
#define PBLK   256        // partition grid size (scan kernel scans PBLK*NSLICE counts)

typedef short bf16x8 __attribute__((ext_vector_type(8)));
typedef float f32x4  __attribute__((ext_vector_type(4)));

// round-to-nearest-even f32 -> bf16 bits
static __device__ __forceinline__ unsigned short f2bf(float f)
{
    unsigned int u = __float_as_uint(f);
    u = (u + 0x7fffu + ((u >> 16) & 1u)) >> 16;
    return (unsigned short)u;
}
static __device__ __forceinline__ unsigned int pack2(float a, float b)
{
    return (unsigned int)f2bf(a) | ((unsigned int)f2bf(b) << 16);
}
// bf16 pair unpack: low half = x<<16, high half = x & 0xffff0000 (1 VALU each)
static __device__ __forceinline__ float lo_f(unsigned int x)
{
    return __uint_as_float(x << 16);
}
static __device__ __forceinline__ float hi_f(unsigned int x)
{
    return __uint_as_float(x & 0xffff0000u);
}
// slice map: ANY deterministic d->[0,8) works as long as count & scatter use
// the IDENTICAL expression.
static __device__ __forceinline__ int slice_of(int d, float sln)
{
    int sl = (int)((float)d * sln);
    return sl > NSLICE - 1 ? NSLICE - 1 : sl;
}

// ---------------------------------------------------------------------------
// K1: blocks [0,PBLK) = per-block per-slice edge counts (no atomics) + zero
// cnt/ovfn + SENTINEL-FILL bucket (all slots -> index n, the zero row).
// Blocks [PBLK,PBLK+16) = weight fragmentize (We 0-7, Ws 8-15).
// Blocks [PBLK+16, ...) = cast h f32 -> hbf bf16 row-major, PLUS row n = 0
// (sentinel row read by padded gather slots).
// ---------------------------------------------------------------------------
__global__ __launch_bounds__(256) void count_fragw_cast(
    const int* __restrict__ dst, int* __restrict__ blockCnt,
    int* __restrict__ cnt, int* __restrict__ ovfn, int E, int n, float sln,
    const float* __restrict__ We, const float* __restrict__ Ws,
    unsigned short* __restrict__ Be, unsigned short* __restrict__ Bs,
    const float* __restrict__ h, unsigned short* __restrict__ hbf, int total,
    unsigned int* __restrict__ bucket32, unsigned int sent2)
{
    int t = threadIdx.x, b = blockIdx.x;

    if (b >= PBLK + 16) {   // ---- cast h -> hbf (+ zero sentinel row n) ----
        int idx = (b - PBLK - 16) * 2048 + t * 8;
        if (idx + 8 <= total) {
            float4 v0 = *(const float4*)&h[idx];
            float4 v1 = *(const float4*)&h[idx + 4];
            uint4 pk;
            pk.x = pack2(v0.x, v0.y);
            pk.y = pack2(v0.z, v0.w);
            pk.z = pack2(v1.x, v1.y);
            pk.w = pack2(v1.z, v1.w);
            *(uint4*)&hbf[idx] = pk;
        } else if (idx + 8 <= total + N_HID) {   // sentinel row = zeros
            uint4 z = {0u, 0u, 0u, 0u};
            *(uint4*)&hbf[idx] = z;
        }
        return;
    }

    if (b >= PBLK) {   // ---- weight fragmentize ----
        int bb = b - PBLK;
        const float* srcw = (bb < 8) ? We : Ws;
        unsigned short* dstF = (bb < 8) ? Be : Bs;
        int rt = bb & 7;
        int kc = t >> 6, l = t & 63, m = l & 15, q = l >> 4;
        const float* p = &srcw[(size_t)(rt * 16 + m) * N_HID + kc * 32 + q * 8];
        float4 v0 = *(const float4*)p;
        float4 v1 = *(const float4*)(p + 4);
        uint4 pk;
        pk.x = pack2(v0.x, v0.y);
        pk.y = pack2(v0.z, v0.w);
        pk.z = pack2(v1.x, v1.y);
        pk.w = pack2(v1.z, v1.w);
        *(uint4*)&dstF[(size_t)rt * 2048 + kc * 512 + l * 8] = pk;
        return;
    }

    // ---- zero cnt/ovfn, sentinel-fill bucket, edge slice counts ----
    for (int i = b * 256 + t; i < n; i += PBLK * 256) cnt[i] = 0;
    {
        const int nb32 = n * (CAP / 2);          // bucket u32 count
        for (int i = b * 256 + t; i < nb32; i += PBLK * 256) bucket32[i] = sent2;
    }
    if (b == 0 && t == 0) *ovfn = 0;

    int c[NSLICE];
#pragma unroll
    for (int s = 0; s < NSLICE; ++s) c[s] = 0;

    for (int e = b * 256 + t; e < E; e += PBLK * 256) {
        int sl = slice_of(dst[e], sln);
#pragma unroll
        for (int s = 0; s < NSLICE; ++s) c[s] += (sl == s);
    }

    __shared__ int red[NSLICE * 4];
    int lane = t & 63, wid = t >> 6;
#pragma unroll
    for (int s = 0; s < NSLICE; ++s) {
        int v = c[s];
#pragma unroll
        for (int off = 32; off; off >>= 1) v += __shfl_down(v, off);
        if (lane == 0) red[s * 4 + wid] = v;
    }
    __syncthreads();
    if (t < NSLICE)
        blockCnt[t * PBLK + b] = red[t*4+0] + red[t*4+1] + red[t*4+2] + red[t*4+3];
}

// ---------------------------------------------------------------------------
// K2: exclusive scan of PBLK*NSLICE counts -> blockBase + sbase[9]. 1 block.
// ---------------------------------------------------------------------------
__global__ __launch_bounds__(256) void part_scan(
    const int* __restrict__ blockCnt, int* __restrict__ blockBase,
    int* __restrict__ sbase, int E)
{
    __shared__ int wsm[4];
    int t = threadIdx.x, lane = t & 63, wid = t >> 6;
    int v[8]; int s = 0;
#pragma unroll
    for (int i = 0; i < 8; ++i) { v[i] = blockCnt[t * 8 + i]; s += v[i]; }
    int val = s;
#pragma unroll
    for (int off = 1; off < 64; off <<= 1) {
        int y = __shfl_up(val, off);
        if (lane >= off) val += y;
    }
    if (lane == 63) wsm[wid] = val;
    __syncthreads();
    if (t == 0) { int a = 0; for (int w = 0; w < 4; ++w) { int tmp = wsm[w]; wsm[w] = a; a += tmp; } }
    __syncthreads();
    int excl = wsm[wid] + val - s;
#pragma unroll
    for (int i = 0; i < 8; ++i) { int tv = v[i]; blockBase[t * 8 + i] = excl; excl += tv; }
    __syncthreads();
    if (t < NSLICE) sbase[t] = blockBase[t * PBLK];
    if (t == 0)     sbase[NSLICE] = E;
}

// ---------------------------------------------------------------------------
// K3: scatter edges into dense per-slice queues using precomputed
// per-(block,slice) bases — only LDS atomics. Packed u32 (d<<16)|s (n<=65536).
// ---------------------------------------------------------------------------
__global__ __launch_bounds__(256) void part_scatter(
    const int* __restrict__ src, const int* __restrict__ dst,
    const int* __restrict__ blockBase, unsigned int* __restrict__ part,
    int E, int n, float sln)
{
    __shared__ int cur[NSLICE];
    int t = threadIdx.x, b = blockIdx.x;
    if (t < NSLICE) cur[t] = blockBase[t * PBLK + b];
    __syncthreads();
    for (int e = b * 256 + t; e < E; e += PBLK * 256) {
        int d = dst[e], s = src[e];
        int sl  = slice_of(d, sln);
        int pos = atomicAdd(&cur[sl], 1);
        part[pos] = ((unsigned int)d << 16) | (unsigned int)s;
    }
}

// ---------------------------------------------------------------------------
// K4: bucket scatter over DENSE per-slice lists. slice = blockIdx&7
// (XCD-affine under round-robin dispatch) -> cnt/bucket lines written from
// ~one XCD. ushort entries, CAP=32 -> one 64B line per node.
// ---------------------------------------------------------------------------
__global__ __launch_bounds__(256) void bucket_scatter2(
    const unsigned int* __restrict__ part,
    const int* __restrict__ sbase,
    int* __restrict__ cnt,
    unsigned short* __restrict__ bucket,
    int* __restrict__ ovfn,
    long long* __restrict__ ovf)
{
    const int slice = blockIdx.x & 7;
    const int g     = blockIdx.x >> 3;
    const int nG    = (int)(gridDim.x >> 3);
    const int lo    = sbase[slice];
    const int hi    = sbase[slice + 1];
    const int m     = hi - lo;

    const int chunk = (m + nG - 1) / nG;
    const int e0 = lo + g * chunk;
    int e1 = e0 + chunk; if (e1 > hi) e1 = hi;

    for (int e = e0 + (int)threadIdx.x; e < e1; e += 256) {
        unsigned int pk = part[e];
        int d = (int)(pk >> 16);
        int s = (int)(pk & 0xffffu);
        int c = atomicAdd(&cnt[d], 1);
        if (c < CAP) {
            bucket[(size_t)d * CAP + c] = (unsigned short)s;
        } else {
            int o = atomicAdd(ovfn, 1);
            if (o < OVF_CAP) ovf[o] = ((long long)d << 32) | (unsigned int)s;
        }
    }
}

// ---------------------------------------------------------------------------
// K5 (fused gather_mean + gemm): one 16-row tile per block, 512 threads =
// 8 waves. Wave w gathers nodes {2w, 2w+1} (serial depth halved vs 4/wave);
// GEMM phase: wave w computes column tile ct=w.
// Gather chain is pure load->load: slot indices read as broadcast ushort
// loads (no shfl in the address path), buckets are SENTINEL-PADDED (index n
// = zero row) so the inner loop has no masks, clamps, or per-slot branches.
// Only wave-uniform branch: skip batch 1 when deg<=16.
// Means packed to LDS [16][68] u32 (stride 272B avoids bank conflicts).
// blockIdx&7 == slice keeps cnt/bucket reads XCD-affine with their writers.
// ---------------------------------------------------------------------------
__global__ __launch_bounds__(512) void gather_gemm(
    const int* __restrict__ cnt,
    const unsigned short* __restrict__ bucket,
    const int* __restrict__ ovfn,
    const long long* __restrict__ ovf,
    const unsigned short* __restrict__ hbf,
    const unsigned short* __restrict__ Be,
    const unsigned short* __restrict__ Bsf,
    const float* __restrict__ bias,
    float* __restrict__ out,
    int n, int nrt)
{
    __shared__ __align__(16) unsigned int wl[16 * 68];   // 4352 B

    const int t    = threadIdx.x;
    const int wid  = t >> 6;          // 0..7
    const int lane = t & 63;
    const int q    = lane >> 4;       // row-group 0..3
    const int s    = lane & 15;       // 16B chunk within row
    const int slice = blockIdx.x & 7;
    const int g     = blockIdx.x >> 3;
    const int tLo = (int)(((long long)slice * nrt) >> 3);
    const int tHi = (int)(((long long)(slice + 1) * nrt) >> 3);
    const int tile = tLo + g;
    if (tile >= tHi) return;          // uniform across block

    const uint4* h4 = (const uint4*)hbf;            // 16 uint4 per row

    // ---- gather phase: 2 nodes per wave ----
#pragma unroll
    for (int k = 0; k < 2; ++k) {
        const int mm   = wid * 2 + k;
        const int node = tile * 16 + mm;          // node < nrt*16; n==nrt*16 here
        const unsigned short* bk = &bucket[(size_t)node * CAP];
        float a0=0.f,a1=0.f,a2=0.f,a3=0.f,a4=0.f,a5=0.f,a6=0.f,a7=0.f;
        int deg = node < n ? cnt[node] : 0;

        // batch 0: slots 0..15 (sentinel-padded -> always safe)
        {
            uint4 vr[4];
#pragma unroll
            for (int i = 0; i < 4; ++i) {
                int r = bk[i * 4 + q];            // broadcast ushort load
                vr[i] = h4[(size_t)r * 16 + s];
            }
#pragma unroll
            for (int i = 0; i < 4; ++i) {
                a0 += lo_f(vr[i].x); a1 += hi_f(vr[i].x);
                a2 += lo_f(vr[i].y); a3 += hi_f(vr[i].y);
                a4 += lo_f(vr[i].z); a5 += hi_f(vr[i].z);
                a6 += lo_f(vr[i].w); a7 += hi_f(vr[i].w);
            }
        }
        // batch 1: slots 16..31 (wave-uniform skip)
        if (deg > 16) {
            uint4 vr[4];
#pragma unroll
            for (int i = 0; i < 4; ++i) {
                int r = bk[16 + i * 4 + q];
                vr[i] = h4[(size_t)r * 16 + s];
            }
#pragma unroll
            for (int i = 0; i < 4; ++i) {
                a0 += lo_f(vr[i].x); a1 += hi_f(vr[i].x);
                a2 += lo_f(vr[i].y); a3 += hi_f(vr[i].y);
                a4 += lo_f(vr[i].z); a5 += hi_f(vr[i].z);
                a6 += lo_f(vr[i].w); a7 += hi_f(vr[i].w);
            }
        }

        if (deg > CAP) {             // exact fallback; few nodes hit it
            int no = *ovfn; if (no > OVF_CAP) no = OVF_CAP;
            unsigned int qm = (q == 0) ? 0xffffffffu : 0u;
            for (int o = 0; o < no; ++o) {
                long long pk = ovf[o];
                if ((int)(pk >> 32) == node) {
                    uint4 v = h4[(size_t)(unsigned int)pk * 16 + s];
                    unsigned int x;
                    x = v.x & qm; a0 += lo_f(x); a1 += hi_f(x);
                    x = v.y & qm; a2 += lo_f(x); a3 += hi_f(x);
                    x = v.z & qm; a4 += lo_f(x); a5 += hi_f(x);
                    x = v.w & qm; a6 += lo_f(x); a7 += hi_f(x);
                }
            }
        }

        // cross-group combine: lanes {l, l^16, l^32, l^48} -> total
#pragma unroll
        for (int off = 16; off <= 32; off <<= 1) {
            a0 += __shfl_xor(a0, off); a1 += __shfl_xor(a1, off);
            a2 += __shfl_xor(a2, off); a3 += __shfl_xor(a3, off);
            a4 += __shfl_xor(a4, off); a5 += __shfl_xor(a5, off);
            a6 += __shfl_xor(a6, off); a7 += __shfl_xor(a7, off);
        }

        float sc = deg > 0 ? 1.0f / (float)deg : 0.f;
        if (q == 0) {                    // lane s writes u32 words 4s..4s+3
            uint4 pk;
            pk.x = pack2(a0 * sc, a1 * sc);
            pk.y = pack2(a2 * sc, a3 * sc);
            pk.z = pack2(a4 * sc, a5 * sc);
            pk.w = pack2(a6 * sc, a7 * sc);
            *(uint4*)&wl[mm * 68 + 4 * s] = pk;
        }
    }
    __syncthreads();

    // ---- GEMM phase: wave w handles column tile ct = w ----
    const int rr = lane & 15, qq = lane >> 4;
    const int row0 = tile * 16;

    bf16x8 ah[4], ag[4];
#pragma unroll
    for (int kc = 0; kc < 4; ++kc) {
        int gr = row0 + rr; if (gr > n - 1) gr = n - 1;
        ah[kc] = *(const bf16x8*)&hbf[(size_t)gr * N_HID + kc * 32 + qq * 8];
        // A-frag: row rr, u32 cols kc*16 + qq*4 .. +3 (padded stride 68)
        ag[kc] = *(const bf16x8*)&wl[rr * 68 + kc * 16 + qq * 4];
    }

    const int colb = lane & 15;
    const int rq   = (lane >> 4) * 4;

    {
        int ct = wid;
        const bf16x8* BpS = (const bf16x8*)(Bsf + (size_t)ct * 2048);
        const bf16x8* BpE = (const bf16x8*)(Be  + (size_t)ct * 2048);
        f32x4 acc = {0.f, 0.f, 0.f, 0.f};
        acc = __builtin_amdgcn_mfma_f32_16x16x32_bf16(ah[0], BpS[lane],       acc, 0, 0, 0);
        acc = __builtin_amdgcn_mfma_f32_16x16x32_bf16(ah[1], BpS[64 + lane],  acc, 0, 0, 0);
        acc = __builtin_amdgcn_mfma_f32_16x16x32_bf16(ah[2], BpS[128 + lane], acc, 0, 0, 0);
        acc = __builtin_amdgcn_mfma_f32_16x16x32_bf16(ah[3], BpS[192 + lane], acc, 0, 0, 0);
        acc = __builtin_amdgcn_mfma_f32_16x16x32_bf16(ag[0], BpE[lane],       acc, 0, 0, 0);
        acc = __builtin_amdgcn_mfma_f32_16x16x32_bf16(ag[1], BpE[64 + lane],  acc, 0, 0, 0);
        acc = __builtin_amdgcn_mfma_f32_16x16x32_bf16(ag[2], BpE[128 + lane], acc, 0, 0, 0);
        acc = __builtin_amdgcn_mfma_f32_16x16x32_bf16(ag[3], BpE[192 + lane], acc, 0, 0, 0);

        int col = ct * 16 + colb;
        float bv = bias[col];
#pragma unroll
        for (int r = 0; r < 4; ++r) {
            int row = row0 + rq + r;
            if (row < n) out[(size_t)row * N_HID + col] = fmaxf(acc[r] + bv, 0.f);
        }
    }
}

// ---------------------------------------------------------------------------
extern "C" void kernel_launch(void* const* d_in, const int* in_sizes, int n_in,
                              void* d_out, int out_size, void* d_ws, size_t ws_size,
                              hipStream_t stream)
{
    const float* h   = (const float*)d_in[0];
    const int*   src = (const int*)d_in[1];
    const int*   dst = (const int*)d_in[2];
    const float* We  = (const float*)d_in[3];
    const float* Ws  = (const float*)d_in[4];
    const float* bs  = (const float*)d_in[5];
    float*       out = (float*)d_out;

    const int n   = in_sizes[0] / N_HID;    // 50000
    const int E   = in_sizes[1];            // 800000
    const int nrt = (n + 15) / 16;          // 3125 row tiles
    const float sln = (float)NSLICE / (float)n;
    const int total = n * N_HID;

    // workspace (~20 MB of the 256 MiB d_ws)
    unsigned short* hbf  = (unsigned short*)d_ws;             // (n+1)*128 bf16 (row n = zero sentinel)
    unsigned short* bucket = hbf + (size_t)(n + 1) * N_HID;   // n*CAP ushort (3.2 MB)
    unsigned short* Be  = bucket + (size_t)n * CAP;           // 8*2048
    unsigned short* Bs  = Be + 8 * 2048;                      // 8*2048
    int*  cnt  = (int*)(Bs + 8 * 2048);                       // n
    int*  ovfn = cnt + n;                                     // 1 (+pad)
    long long* ovf = (long long*)(ovfn + 8);                  // OVF_CAP
    int*  blockCnt  = (int*)(ovf + OVF_CAP);                  // PBLK*NSLICE
    int*  blockBase = blockCnt + PBLK * NSLICE;               // PBLK*NSLICE
    int*  sbase     = blockBase + PBLK * NSLICE;              // 9 (+pad)
    unsigned int* part = (unsigned int*)(sbase + 16);         // E u32 (3.2 MB)

    const unsigned int sent2 = (unsigned int)n | ((unsigned int)n << 16);
    const int castBlocks = (total + N_HID + 2047) / 2048;     // covers rows 0..n

    // fused gather+gemm grid: one tile per block, blockIdx&7 = slice
    const int maxTilesPerSlice = (nrt + NSLICE - 1) / NSLICE; // 391
    const int ggGrid = NSLICE * maxTilesPerSlice;             // 3128

    count_fragw_cast<<<PBLK + 16 + castBlocks, 256, 0, stream>>>(
        dst, blockCnt, cnt, ovfn, E, n, sln, We, Ws, Be, Bs, h, hbf, total,
        (unsigned int*)bucket, sent2);
    part_scan<<<1, 256, 0, stream>>>(blockCnt, blockBase, sbase, E);
    part_scatter<<<PBLK, 256, 0, stream>>>(src, dst, blockBase, part, E, n, sln);
    bucket_scatter2<<<1024, 256, 0, stream>>>(part, sbase, cnt, bucket, ovfn, ovf);
    gather_gemm<<<ggGrid, 512, 0, stream>>>(cnt, bucket, ovfn, ovf,
                                            hbf, Be, Bs, bs, out, n, nrt);
}

// Round 6
// 173.718 us; speedup vs baseline: 1.0348x; 1.0348x over previous
//
#include <hip/hip_runtime.h>

#define N_HID 128
#define CAP   32          // bucket slots per node = exactly one 64B line (ushort)
#define OVF_CAP 8192
#define NSLICE 8
#define PBLK   256        // partition grid size (scan kernel scans PBLK*NSLICE counts)

typedef short bf16x8 __attribute__((ext_vector_type(8)));
typedef float f32x4  __attribute__((ext_vector_type(4)));

// round-to-nearest-even f32 -> bf16 bits
static __device__ __forceinline__ unsigned short f2bf(float f)
{
    unsigned int u = __float_as_uint(f);
    u = (u + 0x7fffu + ((u >> 16) & 1u)) >> 16;
    return (unsigned short)u;
}
static __device__ __forceinline__ unsigned int pack2(float a, float b)
{
    return (unsigned int)f2bf(a) | ((unsigned int)f2bf(b) << 16);
}
// bf16 pair unpack: low half = x<<16, high half = x & 0xffff0000 (1 VALU each)
static __device__ __forceinline__ float lo_f(unsigned int x)
{
    return __uint_as_float(x << 16);
}
static __device__ __forceinline__ float hi_f(unsigned int x)
{
    return __uint_as_float(x & 0xffff0000u);
}
// slice map: ANY deterministic d->[0,8) works as long as count & scatter use
// the IDENTICAL expression.
static __device__ __forceinline__ int slice_of(int d, float sln)
{
    int sl = (int)((float)d * sln);
    return sl > NSLICE - 1 ? NSLICE - 1 : sl;
}

// ---------------------------------------------------------------------------
// K1: blocks [0,PBLK) = per-block per-slice edge counts (no atomics) + zero
// cnt/ovfn + SENTINEL-FILL bucket (all slots -> index n, the zero row).
// Blocks [PBLK,PBLK+16) = weight fragmentize (We 0-7, Ws 8-15).
// Blocks [PBLK+16, ...) = cast h f32 -> hbf bf16 row-major, PLUS row n = 0
// (sentinel row read by padded gather slots).
// ---------------------------------------------------------------------------
__global__ __launch_bounds__(256) void count_fragw_cast(
    const int* __restrict__ dst, int* __restrict__ blockCnt,
    int* __restrict__ cnt, int* __restrict__ ovfn, int E, int n, float sln,
    const float* __restrict__ We, const float* __restrict__ Ws,
    unsigned short* __restrict__ Be, unsigned short* __restrict__ Bs,
    const float* __restrict__ h, unsigned short* __restrict__ hbf, int total,
    unsigned int* __restrict__ bucket32, unsigned int sent2)
{
    int t = threadIdx.x, b = blockIdx.x;

    if (b >= PBLK + 16) {   // ---- cast h -> hbf (+ zero sentinel row n) ----
        int idx = (b - PBLK - 16) * 2048 + t * 8;
        if (idx + 8 <= total) {
            float4 v0 = *(const float4*)&h[idx];
            float4 v1 = *(const float4*)&h[idx + 4];
            uint4 pk;
            pk.x = pack2(v0.x, v0.y);
            pk.y = pack2(v0.z, v0.w);
            pk.z = pack2(v1.x, v1.y);
            pk.w = pack2(v1.z, v1.w);
            *(uint4*)&hbf[idx] = pk;
        } else if (idx + 8 <= total + N_HID) {   // sentinel row = zeros
            uint4 z = {0u, 0u, 0u, 0u};
            *(uint4*)&hbf[idx] = z;
        }
        return;
    }

    if (b >= PBLK) {   // ---- weight fragmentize ----
        int bb = b - PBLK;
        const float* srcw = (bb < 8) ? We : Ws;
        unsigned short* dstF = (bb < 8) ? Be : Bs;
        int rt = bb & 7;
        int kc = t >> 6, l = t & 63, m = l & 15, q = l >> 4;
        const float* p = &srcw[(size_t)(rt * 16 + m) * N_HID + kc * 32 + q * 8];
        float4 v0 = *(const float4*)p;
        float4 v1 = *(const float4*)(p + 4);
        uint4 pk;
        pk.x = pack2(v0.x, v0.y);
        pk.y = pack2(v0.z, v0.w);
        pk.z = pack2(v1.x, v1.y);
        pk.w = pack2(v1.z, v1.w);
        *(uint4*)&dstF[(size_t)rt * 2048 + kc * 512 + l * 8] = pk;
        return;
    }

    // ---- zero cnt/ovfn, sentinel-fill bucket, edge slice counts ----
    for (int i = b * 256 + t; i < n; i += PBLK * 256) cnt[i] = 0;
    {
        const int nb32 = n * (CAP / 2);          // bucket u32 count
        for (int i = b * 256 + t; i < nb32; i += PBLK * 256) bucket32[i] = sent2;
    }
    if (b == 0 && t == 0) *ovfn = 0;

    int c[NSLICE];
#pragma unroll
    for (int s = 0; s < NSLICE; ++s) c[s] = 0;

    for (int e = b * 256 + t; e < E; e += PBLK * 256) {
        int sl = slice_of(dst[e], sln);
#pragma unroll
        for (int s = 0; s < NSLICE; ++s) c[s] += (sl == s);
    }

    __shared__ int red[NSLICE * 4];
    int lane = t & 63, wid = t >> 6;
#pragma unroll
    for (int s = 0; s < NSLICE; ++s) {
        int v = c[s];
#pragma unroll
        for (int off = 32; off; off >>= 1) v += __shfl_down(v, off);
        if (lane == 0) red[s * 4 + wid] = v;
    }
    __syncthreads();
    if (t < NSLICE)
        blockCnt[t * PBLK + b] = red[t*4+0] + red[t*4+1] + red[t*4+2] + red[t*4+3];
}

// ---------------------------------------------------------------------------
// K2: exclusive scan of PBLK*NSLICE counts -> blockBase + sbase[9]. 1 block.
// ---------------------------------------------------------------------------
__global__ __launch_bounds__(256) void part_scan(
    const int* __restrict__ blockCnt, int* __restrict__ blockBase,
    int* __restrict__ sbase, int E)
{
    __shared__ int wsm[4];
    int t = threadIdx.x, lane = t & 63, wid = t >> 6;
    int v[8]; int s = 0;
#pragma unroll
    for (int i = 0; i < 8; ++i) { v[i] = blockCnt[t * 8 + i]; s += v[i]; }
    int val = s;
#pragma unroll
    for (int off = 1; off < 64; off <<= 1) {
        int y = __shfl_up(val, off);
        if (lane >= off) val += y;
    }
    if (lane == 63) wsm[wid] = val;
    __syncthreads();
    if (t == 0) { int a = 0; for (int w = 0; w < 4; ++w) { int tmp = wsm[w]; wsm[w] = a; a += tmp; } }
    __syncthreads();
    int excl = wsm[wid] + val - s;
#pragma unroll
    for (int i = 0; i < 8; ++i) { int tv = v[i]; blockBase[t * 8 + i] = excl; excl += tv; }
    __syncthreads();
    if (t < NSLICE) sbase[t] = blockBase[t * PBLK];
    if (t == 0)     sbase[NSLICE] = E;
}

// ---------------------------------------------------------------------------
// K3: scatter edges into dense per-slice queues using precomputed
// per-(block,slice) bases — only LDS atomics. Packed u32 (d<<16)|s (n<=65536).
// ---------------------------------------------------------------------------
__global__ __launch_bounds__(256) void part_scatter(
    const int* __restrict__ src, const int* __restrict__ dst,
    const int* __restrict__ blockBase, unsigned int* __restrict__ part,
    int E, int n, float sln)
{
    __shared__ int cur[NSLICE];
    int t = threadIdx.x, b = blockIdx.x;
    if (t < NSLICE) cur[t] = blockBase[t * PBLK + b];
    __syncthreads();
    for (int e = b * 256 + t; e < E; e += PBLK * 256) {
        int d = dst[e], s = src[e];
        int sl  = slice_of(d, sln);
        int pos = atomicAdd(&cur[sl], 1);
        part[pos] = ((unsigned int)d << 16) | (unsigned int)s;
    }
}

// ---------------------------------------------------------------------------
// K4: bucket scatter over DENSE per-slice lists. slice = blockIdx&7
// (XCD-affine under round-robin dispatch) -> cnt/bucket lines written from
// ~one XCD. ushort entries, CAP=32 -> one 64B line per node.
// ---------------------------------------------------------------------------
__global__ __launch_bounds__(256) void bucket_scatter2(
    const unsigned int* __restrict__ part,
    const int* __restrict__ sbase,
    int* __restrict__ cnt,
    unsigned short* __restrict__ bucket,
    int* __restrict__ ovfn,
    long long* __restrict__ ovf)
{
    const int slice = blockIdx.x & 7;
    const int g     = blockIdx.x >> 3;
    const int nG    = (int)(gridDim.x >> 3);
    const int lo    = sbase[slice];
    const int hi    = sbase[slice + 1];
    const int m     = hi - lo;

    const int chunk = (m + nG - 1) / nG;
    const int e0 = lo + g * chunk;
    int e1 = e0 + chunk; if (e1 > hi) e1 = hi;

    for (int e = e0 + (int)threadIdx.x; e < e1; e += 256) {
        unsigned int pk = part[e];
        int d = (int)(pk >> 16);
        int s = (int)(pk & 0xffffu);
        int c = atomicAdd(&cnt[d], 1);
        if (c < CAP) {
            bucket[(size_t)d * CAP + c] = (unsigned short)s;
        } else {
            int o = atomicAdd(ovfn, 1);
            if (o < OVF_CAP) ovf[o] = ((long long)d << 32) | (unsigned int)s;
        }
    }
}

// ---------------------------------------------------------------------------
// K5 (fused gather_mean + gemm), v3: one 16-row tile per block, 256 threads
// = 4 waves, 4 nodes per wave. NEW gather core:
//   - node id / cnt / bucket line forced wave-uniform via readfirstlane ->
//     SGPR loads (s_load_dwordx16 pulls the 64B bucket line; SALU index
//     extraction). The VECTOR address path is empty: row loads are
//     s[base] + lane*4 — no VALU, no cross-lane ops before issue.
//   - one row per instruction, fully coalesced (64 lanes x 4B = 256B);
//     lane owns column pair {2l, 2l+1} -> NO cross-lane reduce at all.
//   - 16-deep MLP: batch of 16 loads buffered in an unrolled reg array.
//   - sentinel-padded buckets (index n = zero row): branchless inner loop;
//     single wave-uniform branch skips slots 16..31 when deg<=16.
// Means packed to LDS [16][68] u32; GEMM: wave w -> column tiles 2w, 2w+1.
// blockIdx&7 == slice keeps cnt/bucket reads XCD-affine with their writers.
// ---------------------------------------------------------------------------
__global__ __launch_bounds__(256) void gather_gemm(
    const int* __restrict__ cnt,
    const unsigned short* __restrict__ bucket,
    const int* __restrict__ ovfn,
    const long long* __restrict__ ovf,
    const unsigned short* __restrict__ hbf,
    const unsigned short* __restrict__ Be,
    const unsigned short* __restrict__ Bsf,
    const float* __restrict__ bias,
    float* __restrict__ out,
    int n, int nrt)
{
    __shared__ __align__(16) unsigned int wl[16 * 68];   // 4352 B

    const int t    = threadIdx.x;
    const int lane = t & 63;
    const int widu = __builtin_amdgcn_readfirstlane(t >> 6);   // uniform wave id
    const int slice = blockIdx.x & 7;
    const int g     = blockIdx.x >> 3;
    const int tLo = (int)(((long long)slice * nrt) >> 3);
    const int tHi = (int)(((long long)(slice + 1) * nrt) >> 3);
    const int tile = tLo + g;
    if (tile >= tHi) return;          // uniform across block

    const unsigned int* h32 = (const unsigned int*)hbf;   // 64 uints per row

    // ---- gather phase: 4 nodes per wave, full-wave coalesced rows ----
#pragma unroll
    for (int k = 0; k < 4; ++k) {
        const int mm   = widu * 4 + k;
        const int node = tile * 16 + mm;
        float ax = 0.f, ay = 0.f;
        int deg = 0;
        if (node < n) {                               // wave-uniform
            deg = cnt[node];                          // scalar load
            const unsigned short* bk = &bucket[(size_t)node * CAP];

            // batch 0: slots 0..15 (sentinel-padded -> always safe)
            {
                unsigned int v[16];
#pragma unroll
                for (int i = 0; i < 16; ++i) {
                    const unsigned int r = bk[i];     // SALU extract from s_load
                    v[i] = h32[(size_t)r * 64 + lane];
                }
#pragma unroll
                for (int i = 0; i < 16; ++i) {
                    ax += lo_f(v[i]); ay += hi_f(v[i]);
                }
            }
            // batch 1: slots 16..31 (wave-uniform skip)
            if (deg > 16) {
                unsigned int v[16];
#pragma unroll
                for (int i = 0; i < 16; ++i) {
                    const unsigned int r = bk[16 + i];
                    v[i] = h32[(size_t)r * 64 + lane];
                }
#pragma unroll
                for (int i = 0; i < 16; ++i) {
                    ax += lo_f(v[i]); ay += hi_f(v[i]);
                }
            }

            if (deg > CAP) {             // exact fallback; few nodes hit it
                int no = *ovfn; if (no > OVF_CAP) no = OVF_CAP;
                for (int o = 0; o < no; ++o) {
                    long long pk = ovf[o];
                    if ((int)(pk >> 32) == node) {
                        unsigned int x = h32[(size_t)(unsigned int)pk * 64 + lane];
                        ax += lo_f(x); ay += hi_f(x);
                    }
                }
            }
        }

        float sc = deg > 0 ? 1.0f / (float)deg : 0.f;
        // lane holds cols {2*lane, 2*lane+1}: word `lane` of node mm's row
        wl[mm * 68 + lane] = pack2(ax * sc, ay * sc);
    }
    __syncthreads();

    // ---- GEMM phase: 4 waves split the 8 column tiles (2 each) ----
    const int rr = lane & 15, qq = lane >> 4;
    const int row0 = tile * 16;

    bf16x8 ah[4], ag[4];
#pragma unroll
    for (int kc = 0; kc < 4; ++kc) {
        int gr = row0 + rr; if (gr > n - 1) gr = n - 1;
        ah[kc] = *(const bf16x8*)&hbf[(size_t)gr * N_HID + kc * 32 + qq * 8];
        // A-frag: row rr, u32 cols kc*16 + qq*4 .. +3 (padded stride 68)
        ag[kc] = *(const bf16x8*)&wl[rr * 68 + kc * 16 + qq * 4];
    }

    const int colb = lane & 15;
    const int rq   = (lane >> 4) * 4;

#pragma unroll
    for (int cti = 0; cti < 2; ++cti) {
        int ct = widu * 2 + cti;
        const bf16x8* BpS = (const bf16x8*)(Bsf + (size_t)ct * 2048);
        const bf16x8* BpE = (const bf16x8*)(Be  + (size_t)ct * 2048);
        f32x4 acc = {0.f, 0.f, 0.f, 0.f};
        acc = __builtin_amdgcn_mfma_f32_16x16x32_bf16(ah[0], BpS[lane],       acc, 0, 0, 0);
        acc = __builtin_amdgcn_mfma_f32_16x16x32_bf16(ah[1], BpS[64 + lane],  acc, 0, 0, 0);
        acc = __builtin_amdgcn_mfma_f32_16x16x32_bf16(ah[2], BpS[128 + lane], acc, 0, 0, 0);
        acc = __builtin_amdgcn_mfma_f32_16x16x32_bf16(ah[3], BpS[192 + lane], acc, 0, 0, 0);
        acc = __builtin_amdgcn_mfma_f32_16x16x32_bf16(ag[0], BpE[lane],       acc, 0, 0, 0);
        acc = __builtin_amdgcn_mfma_f32_16x16x32_bf16(ag[1], BpE[64 + lane],  acc, 0, 0, 0);
        acc = __builtin_amdgcn_mfma_f32_16x16x32_bf16(ag[2], BpE[128 + lane], acc, 0, 0, 0);
        acc = __builtin_amdgcn_mfma_f32_16x16x32_bf16(ag[3], BpE[192 + lane], acc, 0, 0, 0);

        int col = ct * 16 + colb;
        float bv = bias[col];
#pragma unroll
        for (int r = 0; r < 4; ++r) {
            int row = row0 + rq + r;
            if (row < n) out[(size_t)row * N_HID + col] = fmaxf(acc[r] + bv, 0.f);
        }
    }
}

// ---------------------------------------------------------------------------
extern "C" void kernel_launch(void* const* d_in, const int* in_sizes, int n_in,
                              void* d_out, int out_size, void* d_ws, size_t ws_size,
                              hipStream_t stream)
{
    const float* h   = (const float*)d_in[0];
    const int*   src = (const int*)d_in[1];
    const int*   dst = (const int*)d_in[2];
    const float* We  = (const float*)d_in[3];
    const float* Ws  = (const float*)d_in[4];
    const float* bs  = (const float*)d_in[5];
    float*       out = (float*)d_out;

    const int n   = in_sizes[0] / N_HID;    // 50000
    const int E   = in_sizes[1];            // 800000
    const int nrt = (n + 15) / 16;          // 3125 row tiles
    const float sln = (float)NSLICE / (float)n;
    const int total = n * N_HID;

    // workspace (~20 MB of the 256 MiB d_ws)
    unsigned short* hbf  = (unsigned short*)d_ws;             // (n+1)*128 bf16 (row n = zero sentinel)
    unsigned short* bucket = hbf + (size_t)(n + 1) * N_HID;   // n*CAP ushort (3.2 MB)
    unsigned short* Be  = bucket + (size_t)n * CAP;           // 8*2048
    unsigned short* Bs  = Be + 8 * 2048;                      // 8*2048
    int*  cnt  = (int*)(Bs + 8 * 2048);                       // n
    int*  ovfn = cnt + n;                                     // 1 (+pad)
    long long* ovf = (long long*)(ovfn + 8);                  // OVF_CAP
    int*  blockCnt  = (int*)(ovf + OVF_CAP);                  // PBLK*NSLICE
    int*  blockBase = blockCnt + PBLK * NSLICE;               // PBLK*NSLICE
    int*  sbase     = blockBase + PBLK * NSLICE;              // 9 (+pad)
    unsigned int* part = (unsigned int*)(sbase + 16);         // E u32 (3.2 MB)

    const unsigned int sent2 = (unsigned int)n | ((unsigned int)n << 16);
    const int castBlocks = (total + N_HID + 2047) / 2048;     // covers rows 0..n

    // fused gather+gemm grid: one tile per block, blockIdx&7 = slice
    const int maxTilesPerSlice = (nrt + NSLICE - 1) / NSLICE; // 391
    const int ggGrid = NSLICE * maxTilesPerSlice;             // 3128

    count_fragw_cast<<<PBLK + 16 + castBlocks, 256, 0, stream>>>(
        dst, blockCnt, cnt, ovfn, E, n, sln, We, Ws, Be, Bs, h, hbf, total,
        (unsigned int*)bucket, sent2);
    part_scan<<<1, 256, 0, stream>>>(blockCnt, blockBase, sbase, E);
    part_scatter<<<PBLK, 256, 0, stream>>>(src, dst, blockBase, part, E, n, sln);
    bucket_scatter2<<<1024, 256, 0, stream>>>(part, sbase, cnt, bucket, ovfn, ovf);
    gather_gemm<<<ggGrid, 256, 0, stream>>>(cnt, bucket, ovfn, ovf,
                                            hbf, Be, Bs, bs, out, n, nrt);
}